// Round 8
// baseline (99.332 us; speedup 1.0000x reference)
//
#include <hip/hip_runtime.h>
#include <math.h>
#include <stdint.h>

#define GAMMA 0.7f
#define QCAP 2048

typedef __attribute__((ext_vector_type(8))) short short8v;   // 8 bf16
typedef __attribute__((ext_vector_type(4))) float f32x4;

__device__ __forceinline__ float sp_dev(float x) {
    return fmaxf(x, 0.0f) + log1pf(expf(-fabsf(x)));
}
__device__ __forceinline__ float gelu_exact(float x) {
    return 0.5f * x * (1.0f + erff(x * 0.70710678118654752f));
}
__device__ __forceinline__ uint16_t f2bf(float x) {
    union { float f; uint32_t u; } c; c.f = x;
    uint32_t u = c.u + 0x7FFFu + ((c.u >> 16) & 1u);
    return (uint16_t)(u >> 16);
}

// ===========================================================================
// K1: role-split grid.
//   blocks [0, BC)            : contrib — one instance per thread, write cont
//   blocks [BC, BC+n)         : rowsum  — one row per block
//   blocks [BC+n, BC+n+BP)    : prep    — bf16 transposed weights
// ===========================================================================
__global__ __launch_bounds__(256) void k1_kernel(
    const float* __restrict__ A, const int* __restrict__ tri, const int* __restrict__ cyc,
    const float* __restrict__ Wt0, const float* __restrict__ Wc0, const float* __restrict__ g0,
    const float* __restrict__ Wt1, const float* __restrict__ Wc1, const float* __restrict__ g1,
    const float* __restrict__ w1_0, const float* __restrict__ w2_0,
    const float* __restrict__ w1_1, const float* __restrict__ w2_1,
    float* __restrict__ cont, float* __restrict__ H0,
    uint16_t* __restrict__ Wb10, uint16_t* __restrict__ Wb20,
    uint16_t* __restrict__ Wb11, uint16_t* __restrict__ Wb21,
    float* __restrict__ out, int n, int Itri, int Icyc, int BC) {

    const int tid = threadIdx.x;
    const int bid = blockIdx.x;
    const int Itot = Itri + Icyc;

    if (bid < BC) {
        // ---------------- contrib ----------------
        __shared__ float dcs[2][2][8][3];   // [m][L][f][p]
        if (tid < 32) {
            int L = tid >> 4, m = (tid >> 3) & 1, f = tid & 7;
            int k = m ? 4 : 3;
            const float* W = L ? (m ? Wc1 : Wt1) : (m ? Wc0 : Wt0);
            const float* g = L ? g1 : g0;
            float S[4][4], Y[4][4];
            for (int a = 0; a < k; a++)
                for (int b = 0; b < k; b++)
                    S[a][b] = sp_dev(W[(f * k + a) * k + b]);
            for (int a = 0; a < k; a++)
                for (int b = 0; b < k; b++)
                    Y[a][b] = (a == b) ? 0.0f : 0.5f * (S[a][b] + S[b][a]);
            for (int a = 0; a < k; a++) {
                float rs = 0.0f;
                for (int b = 0; b < k; b++) rs += Y[a][b];
                rs = fmaxf(rs, 1e-12f);
                for (int b = 0; b < k; b++) Y[a][b] /= rs;
            }
            float t1 = 0, t2 = 0, t3 = 0;
            for (int a = 0; a < k; a++) t1 += Y[a][a];
            for (int a = 0; a < k; a++)
                for (int b = 0; b < k; b++) t2 += Y[a][b] * Y[b][a];
            for (int a = 0; a < k; a++)
                for (int b = 0; b < k; b++)
                    for (int c = 0; c < k; c++) t3 += Y[a][b] * Y[b][c] * Y[c][a];
            dcs[m][L][f][0] = GAMMA * sp_dev(g[0]) * t1;
            dcs[m][L][f][1] = GAMMA * GAMMA * sp_dev(g[1]) * t2;
            dcs[m][L][f][2] = GAMMA * GAMMA * GAMMA * sp_dev(g[2]) * t3;
        }
        __syncthreads();

        int inst = bid * 256 + tid;
        if (inst >= Itot) return;
        bool isTri = inst < Itri;
        int m = isTri ? 0 : 1;
        float kinv = isTri ? (1.0f / 3.0f) : 0.25f;
        int nd[4];
        if (isTri) {
            const int* p = tri + inst * 3;
            nd[0] = p[0]; nd[1] = p[1]; nd[2] = p[2]; nd[3] = 0;
        } else {
            const int* p = cyc + (size_t)(inst - Itri) * 4;
            nd[0] = p[0]; nd[1] = p[1]; nd[2] = p[2]; nd[3] = p[3];
        }
        // padded 4x4 transition matrix (tri: row3=[0,0,0,1], traces -1)
        float M[4][4];
#pragma unroll
        for (int a = 0; a < 4; a++) {
            float rs = 0.0f;
#pragma unroll
            for (int b = 0; b < 4; b++) {
                float v;
                if (isTri)
                    v = (a < 3 && b < 3) ? A[(size_t)nd[a] * n + nd[b]]
                                         : ((a == 3 && b == 3) ? 1.0f : 0.0f);
                else
                    v = A[(size_t)nd[a] * n + nd[b]];
                M[a][b] = v; rs += v;
            }
            rs = fmaxf(rs, 1e-12f);
            float inv = 1.0f / rs;
#pragma unroll
            for (int b = 0; b < 4; b++) M[a][b] *= inv;
        }
        float t1 = M[0][0] + M[1][1] + M[2][2] + M[3][3];
        float t2 = 0, t3 = 0;
#pragma unroll
        for (int a = 0; a < 4; a++)
#pragma unroll
            for (int b = 0; b < 4; b++) {
                float ab = M[a][b];
                t2 += ab * M[b][a];
                float a3 = 0;
#pragma unroll
                for (int c = 0; c < 4; c++) a3 += M[b][c] * M[c][a];
                t3 += ab * a3;
            }
        if (isTri) { t1 -= 1.0f; t2 -= 1.0f; t3 -= 1.0f; }

#pragma unroll
        for (int L = 0; L < 2; L++) {
            float sims[8], mx = -1e30f;
#pragma unroll
            for (int f = 0; f < 8; f++) {
                sims[f] = dcs[m][L][f][0] * t1 + dcs[m][L][f][1] * t2 +
                          dcs[m][L][f][2] * t3;
                mx = fmaxf(mx, sims[f]);
            }
            float es[8], se = 0;
#pragma unroll
            for (int f = 0; f < 8; f++) { es[f] = expf(sims[f] - mx); se += es[f]; }
            float si = 1.0f / se;
            f32x4 c0, c1;
#pragma unroll
            for (int f = 0; f < 4; f++) c0[f] = es[f] * si * sims[f] * kinv;
#pragma unroll
            for (int f = 0; f < 4; f++) c1[f] = es[f + 4] * si * sims[f + 4] * kinv;
            float* cp = cont + ((size_t)L * Itot + inst) * 8;
            *(f32x4*)cp = c0;
            *(f32x4*)(cp + 4) = c1;
        }
    } else if (bid < BC + n) {
        // ---------------- rowsum ----------------
        __shared__ float red[4];
        int row = bid - BC;
        const float4* Arow = (const float4*)(A + (size_t)row * n);
        int n4 = n >> 2;
        float s = 0.0f;
        for (int i = tid; i < n4; i += 256) {
            float4 v = Arow[i];
            s += v.x + v.y + v.z + v.w;
        }
        for (int off = 32; off > 0; off >>= 1) s += __shfl_down(s, off);
        if ((tid & 63) == 0) red[tid >> 6] = s;
        __syncthreads();
        if (tid == 0) {
            float t = red[0] + red[1] + red[2] + red[3];
            H0[row] = t;
            out[(size_t)row * 257 + 256] = t;
        }
    } else {
        // ---------------- prep: bf16 transposed weights ----------------
        int base = (bid - BC - n) * 4096;
        for (int k = 0; k < 16; k++) {
            int idx = base + k * 256 + tid;
            if (idx >= 57344) break;
            if (idx < 4096) {
                int c = idx >> 5, kk = idx & 31;
                Wb10[idx] = (kk < 17) ? f2bf(w1_0[kk * 128 + c]) : 0;
            } else if (idx < 20480) {
                int e = idx - 4096; int c = e >> 7, kk = e & 127;
                Wb20[e] = f2bf(w2_0[kk * 128 + c]);
            } else if (idx < 40960) {
                int e = idx - 20480; int c = e / 160, kk = e % 160;
                Wb11[e] = (kk < 145) ? f2bf(w1_1[kk * 128 + c]) : 0;
            } else {
                int e = idx - 40960; int c = e >> 7, kk = e & 127;
                Wb21[e] = f2bf(w2_1[kk * 128 + c]);
            }
        }
    }
}

// ===========================================================================
// K2: per 16-row tile: scan membership -> drain cont lines into LDS phi ->
// LN0 -> G1_0 -> G2_0 (out cols 128..255) -> LN1 -> G1_1 -> G2_1 (cols 0..127)
// ===========================================================================
__global__ __launch_bounds__(1024) void k2_kernel(
    const int* __restrict__ tri, const int* __restrict__ cyc,
    const float* __restrict__ cont, const float* __restrict__ H0,
    const float* __restrict__ lng0, const float* __restrict__ lnb0,
    const uint16_t* __restrict__ Wb10, const float* __restrict__ b1_0,
    const uint16_t* __restrict__ Wb20, const float* __restrict__ b2_0,
    const float* __restrict__ lng1, const float* __restrict__ lnb1,
    const uint16_t* __restrict__ Wb11, const float* __restrict__ b1_1,
    const uint16_t* __restrict__ Wb21, const float* __restrict__ b2_1,
    float* __restrict__ out, int n, int Itri, int Icyc) {

    // queue (scan/drain) overlays Xs/Hs/Zs (tail) -- disjoint lifetimes
    __shared__ __align__(16) char upool[18432];
    int* queue = (int*)upool;                                 // 8 KB used
    uint16_t (*Xs)[168] = (uint16_t(*)[168])upool;            // 5376 B
    uint16_t (*Hs)[136] = (uint16_t(*)[136])(upool + 5376);   // 4352 B
    float    (*Zs)[132] = (float(*)[132])(upool + 9728);      // 8448 B
    __shared__ float phi[2][16][16];
    __shared__ float h0s[16];
    __shared__ int qcnt;

    const int tid  = threadIdx.x;
    const int v0   = blockIdx.x * 16;
    const int lane = tid & 63;
    const int Itot = Itri + Icyc;

    // ---- init ----
    if (tid < 512) ((float*)phi)[tid] = 0.0f;
    if (tid == 0) qcnt = 0;
    if (tid >= 512 && tid < 528) h0s[tid - 512] = H0[v0 + (tid - 512)];
    __syncthreads();

    // ---- scan: membership test of all instances ----
    for (int base = 0; base < Itot; base += 1024) {
        int inst = base + tid;
        if (inst >= Itot) break;
        int hit = 0;
        if (inst < Itri) {
            const int* p = tri + inst * 3;
#pragma unroll
            for (int j = 0; j < 3; j++) hit |= ((unsigned)(p[j] - v0) < 16u);
        } else {
            const int* p = cyc + (size_t)(inst - Itri) * 4;
#pragma unroll
            for (int j = 0; j < 4; j++) hit |= ((unsigned)(p[j] - v0) < 16u);
        }
        if (hit) {
            int q = atomicAdd(&qcnt, 1);
            if (q < QCAP) queue[q] = inst;
        }
    }
    __syncthreads();

    // ---- drain: item = (hit, L); read cont line, scatter into LDS phi ----
    {
        int qn = qcnt < QCAP ? qcnt : QCAP;
        for (int it = tid; it < 2 * qn; it += 1024) {
            int qi = it >> 1, L = it & 1;
            int inst = queue[qi];
            bool isTri = inst < Itri;
            int K = isTri ? 3 : 4;
            int m = isTri ? 0 : 1;
            const int* p = isTri ? tri + inst * 3 : cyc + (size_t)(inst - Itri) * 4;
            const float* cp = cont + ((size_t)L * Itot + inst) * 8;
            float4 c0 = *(const float4*)cp;
            float4 c1 = *(const float4*)(cp + 4);
#pragma unroll
            for (int j = 0; j < 4; j++) {
                if (j >= K) break;
                int r = p[j] - v0;
                if ((unsigned)r < 16u) {
                    float* dst = &phi[L][r][m * 8];
                    atomicAdd(&dst[0], c0.x); atomicAdd(&dst[1], c0.y);
                    atomicAdd(&dst[2], c0.z); atomicAdd(&dst[3], c0.w);
                    atomicAdd(&dst[4], c1.x); atomicAdd(&dst[5], c1.y);
                    atomicAdd(&dst[6], c1.z); atomicAdd(&dst[7], c1.w);
                }
            }
        }
    }
    __syncthreads();

    // ---- LN0 -> Xs[:,0..31] ----
    if (tid < 512) {
        int r = tid >> 5;
        int j = tid & 31;
        float x = (j < 16) ? phi[0][r][j] : (j == 16 ? h0s[r] : 0.0f);
        float s1 = x, s2 = x * x;
        for (int o = 16; o > 0; o >>= 1) { s1 += __shfl_xor(s1, o); s2 += __shfl_xor(s2, o); }
        float mu = s1 / 17.0f;
        float rstd = rsqrtf(s2 / 17.0f - mu * mu + 1e-5f);
        Xs[r][j] = (j < 17) ? f2bf((x - mu) * rstd * lng0[j] + lnb0[j]) : (uint16_t)0;
    }
    __syncthreads();

    // ---- G1 layer0 (K=32) ----
    if (tid < 512) {
        int w8 = tid >> 6, lr = lane & 15, lg = lane >> 4;
        int col = w8 * 16 + lr;
        f32x4 acc = {0.f, 0.f, 0.f, 0.f};
        short8v a = *(const short8v*)&Xs[lr][lg * 8];
        short8v b = *(const short8v*)(Wb10 + (size_t)col * 32 + lg * 8);
        acc = __builtin_amdgcn_mfma_f32_16x16x32_bf16(a, b, acc, 0, 0, 0);
        float bias = b1_0[col];
#pragma unroll
        for (int i = 0; i < 4; i++)
            Hs[lg * 4 + i][col] = f2bf(gelu_exact(acc[i] + bias));
    }
    __syncthreads();

    // ---- G2 layer0 -> out[:,128..255] + Zs ----
    if (tid < 512) {
        int w8 = tid >> 6, lr = lane & 15, lg = lane >> 4;
        int col = w8 * 16 + lr;
        f32x4 acc = {0.f, 0.f, 0.f, 0.f};
#pragma unroll
        for (int ks = 0; ks < 4; ks++) {
            short8v a = *(const short8v*)&Hs[lr][ks * 32 + lg * 8];
            short8v b = *(const short8v*)(Wb20 + (size_t)col * 128 + ks * 32 + lg * 8);
            acc = __builtin_amdgcn_mfma_f32_16x16x32_bf16(a, b, acc, 0, 0, 0);
        }
        float bias = b2_0[col];
#pragma unroll
        for (int i = 0; i < 4; i++) {
            int row = lg * 4 + i;
            float val = acc[i] + bias;
            out[(size_t)(v0 + row) * 257 + 128 + col] = val;
            Zs[row][col] = val;
        }
    }
    __syncthreads();

    // ---- LN1 -> Xs[:,0..159] ----
    if (tid < 512) {
        int rr = tid >> 5;
        int t = tid & 31;
        float ph[5];
        float s1 = 0.0f, s2 = 0.0f;
#pragma unroll
        for (int s = 0; s < 5; s++) {
            int j = t + 32 * s;
            float x = 0.0f;
            if (j < 16) x = phi[1][rr][j];
            else if (j < 144) x = Zs[rr][j - 16];
            else if (j == 144) x = h0s[rr];
            ph[s] = x;
            if (j < 145) { s1 += x; s2 += x * x; }
        }
        for (int o = 16; o > 0; o >>= 1) { s1 += __shfl_xor(s1, o); s2 += __shfl_xor(s2, o); }
        float mu = s1 / 145.0f;
        float rstd = rsqrtf(s2 / 145.0f - mu * mu + 1e-5f);
#pragma unroll
        for (int s = 0; s < 5; s++) {
            int j = t + 32 * s;
            Xs[rr][j] = (j < 145) ? f2bf((ph[s] - mu) * rstd * lng1[j] + lnb1[j])
                                  : (uint16_t)0;
        }
    }
    __syncthreads();

    // ---- G1 layer1 (K=160) ----
    if (tid < 512) {
        int w8 = tid >> 6, lr = lane & 15, lg = lane >> 4;
        int col = w8 * 16 + lr;
        f32x4 acc = {0.f, 0.f, 0.f, 0.f};
#pragma unroll
        for (int ks = 0; ks < 5; ks++) {
            short8v a = *(const short8v*)&Xs[lr][ks * 32 + lg * 8];
            short8v b = *(const short8v*)(Wb11 + (size_t)col * 160 + ks * 32 + lg * 8);
            acc = __builtin_amdgcn_mfma_f32_16x16x32_bf16(a, b, acc, 0, 0, 0);
        }
        float bias = b1_1[col];
#pragma unroll
        for (int i = 0; i < 4; i++)
            Hs[lg * 4 + i][col] = f2bf(gelu_exact(acc[i] + bias));
    }
    __syncthreads();

    // ---- G2 layer1 -> out[:,0..127] ----
    if (tid < 512) {
        int w8 = tid >> 6, lr = lane & 15, lg = lane >> 4;
        int col = w8 * 16 + lr;
        f32x4 acc = {0.f, 0.f, 0.f, 0.f};
#pragma unroll
        for (int ks = 0; ks < 4; ks++) {
            short8v a = *(const short8v*)&Hs[lr][ks * 32 + lg * 8];
            short8v b = *(const short8v*)(Wb21 + (size_t)col * 128 + ks * 32 + lg * 8);
            acc = __builtin_amdgcn_mfma_f32_16x16x32_bf16(a, b, acc, 0, 0, 0);
        }
        float bias = b2_1[col];
#pragma unroll
        for (int i = 0; i < 4; i++) {
            int row = lg * 4 + i;
            out[(size_t)(v0 + row) * 257 + col] = acc[i] + bias;
        }
    }
}

extern "C" void kernel_launch(void* const* d_in, const int* in_sizes, int n_in,
                              void* d_out, int out_size, void* d_ws, size_t ws_size,
                              hipStream_t stream) {
    const float* A    = (const float*)d_in[0];
    const int*   tri  = (const int*)d_in[1];
    const int*   cyc  = (const int*)d_in[2];

    int n    = out_size / 257;          // 4096
    int Itri = in_sizes[1] / 3;         // 30000
    int Icyc = in_sizes[2] / 4;         // 15000
    int Itot = Itri + Icyc;

    float* ws = (float*)d_ws;
    float* H0   = ws;                                    // n
    float* cont = ws + n;                                // 2*Itot*8
    uint16_t* Wb10 = (uint16_t*)(cont + (size_t)2 * Itot * 8);  // 128*32
    uint16_t* Wb20 = Wb10 + 128 * 32;                    // 128*128
    uint16_t* Wb11 = Wb20 + 128 * 128;                   // 128*160
    uint16_t* Wb21 = Wb11 + 128 * 160;                   // 128*128
    float* out = (float*)d_out;

    int BC = (Itot + 255) / 256;    // 176
    int BP = 14;                    // 57344 / 4096
    k1_kernel<<<BC + n + BP, 256, 0, stream>>>(
        A, tri, cyc,
        (const float*)d_in[3], (const float*)d_in[4], (const float*)d_in[5],
        (const float*)d_in[12], (const float*)d_in[13], (const float*)d_in[14],
        (const float*)d_in[8], (const float*)d_in[10],
        (const float*)d_in[17], (const float*)d_in[19],
        cont, H0, Wb10, Wb20, Wb11, Wb21, out, n, Itri, Icyc, BC);

    k2_kernel<<<n / 16, 1024, 0, stream>>>(
        tri, cyc, cont, H0,
        (const float*)d_in[6], (const float*)d_in[7],
        Wb10, (const float*)d_in[9], Wb20, (const float*)d_in[11],
        (const float*)d_in[15], (const float*)d_in[16],
        Wb11, (const float*)d_in[18], Wb21, (const float*)d_in[20],
        out, n, Itri, Icyc);
}